// Round 10
// baseline (156.394 us; speedup 1.0000x reference)
//
#include <hip/hip_runtime.h>

typedef __attribute__((ext_vector_type(8))) short short8;
typedef __attribute__((ext_vector_type(4))) float floatx4;

// Problem constants
#define NEXP   36          // 12 tempers * 3 ops
#define NTOK   1024        // 128 batch * 8 patches
#define HOPS   4

// Workspace layout (bytes) — no weight copies anymore (r9 fix: prep's bf16
// convert dispatch was 55 us, the single largest controllable cost)
#define OFF_STATE   0u          // 1024*256*4 = 1,048,576
#define OFF_C1      1048576u    // 36*256*4   = 36,864
#define OFF_COUNTS  1085440u    // 4*36*4     = 576
#define OFF_LISTS   1086016u    // 4*36*1024*4= 589,824
#define OFF_JOBS    1675840u    // 4*128*4    = 2,048
#define OFF_NJ      1677888u    // 4*4        = 16    (end ~1.68 MB)

__device__ __forceinline__ unsigned short f2bf(float f) {
    unsigned u = __float_as_uint(f);
    u += 0x7FFFu + ((u >> 16) & 1u);   // round-to-nearest-even
    return (unsigned short)(u >> 16);
}

// ---------------------------------------------------------------------------
// PREP (now tiny: 37 blocks):
//  blocks [0,36) : c1[e][j] = b1[e][j] + sum_k emb[e][k]*W1[e][256+k][j]
//  block  36     : routing + job compaction
// ---------------------------------------------------------------------------
__global__ __launch_bounds__(256) void prep_kernel(
    const float* __restrict__ W1, const float* __restrict__ b1,
    const float* __restrict__ op_emb,
    const int* __restrict__ tempers, const int* __restrict__ ops,
    float* __restrict__ c1, int* __restrict__ counts, int* __restrict__ lists,
    int* __restrict__ jobs, int* __restrict__ njobs)
{
    const int bid = blockIdx.x;
    const int t = threadIdx.x;

    if (bid < 36) {
        // ---- c1 precompute (fp32) ----
        const int e = bid;
        __shared__ float eb[128];
        if (t < 128) eb[t] = op_emb[e * 128 + t];
        __syncthreads();
        float acc = b1[e * 256 + t];
        const float* wp = W1 + e * 98304 + 256 * 256;  // emb rows of W1[e]
        #pragma unroll 4
        for (int k = 0; k < 128; k++)
            acc += eb[k] * wp[k * 256 + t];
        c1[e * 256 + t] = acc;
    } else {
        // ---- routing (single block; cumulative-halt semantics) ----
        __shared__ int lc[HOPS * NEXP];
        if (t < HOPS * NEXP) lc[t] = 0;
        __syncthreads();
        for (int q = 0; q < 4; q++) {
            int n = q * 256 + t;
            bool act = true;
            for (int hop = 0; hop < HOPS; hop++) {
                int tt = tempers[hop * NTOK + n];
                int oo = ops[hop * NTOK + n];
                act = act && (tt != 12);       // 12 == halt; sticky
                if (act) {
                    int e = tt * 3 + oo;
                    int pos = atomicAdd(&lc[hop * NEXP + e], 1);
                    lists[(hop * NEXP + e) * NTOK + pos] = n;
                }
            }
        }
        __syncthreads();
        if (t < HOPS * NEXP) counts[t] = lc[t];
        // ---- job compaction: one thread per hop; job = (m0<<8)|e ----
        if (t < HOPS) {
            int hop = t, nj = 0;
            for (int e = 0; e < NEXP; e++) {
                int c = lc[hop * NEXP + e];
                for (int m0 = 0; m0 < c; m0 += 16)
                    jobs[hop * 128 + nj++] = (m0 << 8) | e;
            }
            njobs[hop] = nj;
        }
    }
}

// ---------------------------------------------------------------------------
// HOP: one job = (expert, 16-token tile), 1024 threads = 16 waves.
// Wave w owns output columns [w*16,w*16+16). B-fragments are built DIRECTLY
// from the original fp32 W1/W2 (64 strided dword loads per GEMM, coalesced
// 256B per instruction across the 16-col group) + in-register RNE convert —
// identical bits to the old prep-converted path, but the 55 us conversion
// dispatch is gone. VALU-produced frags resist load-sinking; pin keeps them
// materialized ahead of the MFMA loops.
//  GEMM1: h = relu(src_bf16 @ bf16(W1[:256]) + c1)   (c1 folds emb+b1)
//  GEMM2: y = relu(h_bf16 @ bf16(W2) + b2)  -> state (f32)
// src = x for hop 0, state for hops 1..3 (sticky halt => rows valid).
// MFMA maps (m89): A[m=l&15][k=(l>>4)*8+i]; B lane l: n=l&15, k=(l>>4)*8+i;
// D col=l&15, row=(l>>4)*4+reg.
// ---------------------------------------------------------------------------
__global__ __launch_bounds__(1024, 4) void hop_kernel(
    const float* __restrict__ src, float* __restrict__ state,
    const float* __restrict__ W1, const float* __restrict__ W2,
    const float* __restrict__ c1, const float* __restrict__ b2,
    const int* __restrict__ counts, const int* __restrict__ lists,
    const int* __restrict__ jobs, const int* __restrict__ njobs, int hop)
{
    if (blockIdx.x >= njobs[hop]) return;  // uniform early-exit
    const int job = jobs[hop * 128 + blockIdx.x];
    const int e   = job & 0xFF;
    const int m0  = job >> 8;
    const int n_e = counts[hop * NEXP + e];
    const int mact = min(16, n_e - m0);

    const int t = threadIdx.x;
    const int l = t & 63, w = t >> 6;      // wave 0..15
    const int col = l & 15, g = l >> 4;
    const int j = w * 16 + col;            // this wave's output column

    // ---- build B-frags from fp32 weights (strided loads + RNE convert) ----
    const float* Wp  = W1 + e * 98304;     // [384][256], rows 0..255 used here
    const float* Wp2 = W2 + e * 65536;     // [256][256]
    short8 B1[8], B2[8];
    #pragma unroll
    for (int kb = 0; kb < 8; kb++) {
        float v1[8], v2[8];
        #pragma unroll
        for (int i = 0; i < 8; i++) {
            int k = kb * 32 + g * 8 + i;
            v1[i] = Wp [k * 256 + j];
            v2[i] = Wp2[k * 256 + j];
        }
        short8 b1v, b2v;
        #pragma unroll
        for (int i = 0; i < 8; i++) {
            b1v[i] = (short)f2bf(v1[i]);
            b2v[i] = (short)f2bf(v2[i]);
        }
        B1[kb] = b1v;
        B2[kb] = b2v;
    }
    // ---- force materialization (defeat any load/convert sinking) ----
    #pragma unroll
    for (int kb = 0; kb < 8; kb++) {
        int4 p1 = __builtin_bit_cast(int4, B1[kb]);
        int4 p2 = __builtin_bit_cast(int4, B2[kb]);
        asm volatile("" : "+v"(p1.x), "+v"(p1.y), "+v"(p1.z), "+v"(p1.w),
                          "+v"(p2.x), "+v"(p2.y), "+v"(p2.z), "+v"(p2.w));
        B1[kb] = __builtin_bit_cast(short8, p1);
        B2[kb] = __builtin_bit_cast(short8, p2);
    }
    const float cv = c1[e * 256 + j];
    const float bv = b2[e * 256 + j];

    __shared__ int toks[16];
    __shared__ unsigned short Ab[4096];    // [kb][lane][8] bf16, 8 KB
    __shared__ unsigned short Hb[4096];    // 8 KB

    if (t < 16) toks[t] = (t < mact) ? lists[(hop * NEXP + e) * NTOK + m0 + t] : 0;
    __syncthreads();

    // ---- stage A tile: src rows (f32) -> bf16 in A-frag layout ----
    {
        int m = t >> 6;                    // token row 0..15 (one wave per row)
        int k = (t & 63) * 4;              // float4 column
        float4 v = make_float4(0.f, 0.f, 0.f, 0.f);
        if (m < mact) v = *(const float4*)(src + toks[m] * 256 + k);
        int kb = k >> 5, gg = (k >> 3) & 3, i = k & 7;
        unsigned short* d = Ab + kb * 512 + (gg * 16 + m) * 8 + i;
        d[0] = f2bf(v.x); d[1] = f2bf(v.y); d[2] = f2bf(v.z); d[3] = f2bf(v.w);
    }
    __syncthreads();

    // ---- GEMM1 (weights in registers) ----
    floatx4 acc = (floatx4){cv, cv, cv, cv};
    #pragma unroll
    for (int kb = 0; kb < 8; kb++) {
        short8 a = *(const short8*)(Ab + kb * 512 + l * 8);
        acc = __builtin_amdgcn_mfma_f32_16x16x32_bf16(a, B1[kb], acc, 0, 0, 0);
    }
    // ---- epilogue 1: relu -> Hb in A-frag layout (h-dim becomes K) ----
    {
        int kb2 = j >> 5, g2 = (j >> 3) & 3, i2 = j & 7;
        #pragma unroll
        for (int r = 0; r < 4; r++) {
            int m = g * 4 + r;             // D row (token)
            float vv = acc[r];
            vv = vv > 0.f ? vv : 0.f;
            Hb[kb2 * 512 + (g2 * 16 + m) * 8 + i2] = f2bf(vv);
        }
    }
    __syncthreads();

    // ---- GEMM2 ----
    floatx4 acc2 = (floatx4){bv, bv, bv, bv};
    #pragma unroll
    for (int kb = 0; kb < 8; kb++) {
        short8 a = *(const short8*)(Hb + kb * 512 + l * 8);
        acc2 = __builtin_amdgcn_mfma_f32_16x16x32_bf16(a, B2[kb], acc2, 0, 0, 0);
    }
    // ---- epilogue 2: relu -> state (f32), only real rows ----
    #pragma unroll
    for (int r = 0; r < 4; r++) {
        int m = g * 4 + r;
        if (m < mact) {
            float vv = acc2[r];
            state[toks[m] * 256 + j] = vv > 0.f ? vv : 0.f;
        }
    }
}

// ---------------------------------------------------------------------------
// FINAL: mean-pool 8 patches -> LayerNorm -> 10-class head. One block/batch.
// Tokens halted at hop 0 (tempers[0][n]==12) were never written -> read x.
// ---------------------------------------------------------------------------
__global__ __launch_bounds__(256) void final_kernel(
    const float* __restrict__ x, const float* __restrict__ state,
    const int* __restrict__ tempers,
    const float* __restrict__ ln_g, const float* __restrict__ ln_b,
    const float* __restrict__ Wt, const float* __restrict__ bt,
    float* __restrict__ out)
{
    const int b = blockIdx.x, t = threadIdx.x;
    float s = 0.f;
    #pragma unroll
    for (int p = 0; p < 8; p++) {
        int n = b * 8 + p;
        const float* rowsrc = (tempers[n] != 12) ? state : x;
        s += rowsrc[n * 256 + t];
    }
    s *= 0.125f;

    float v1 = s, v2 = s * s;
    #pragma unroll
    for (int off = 32; off; off >>= 1) {
        v1 += __shfl_down(v1, off);
        v2 += __shfl_down(v2, off);
    }
    __shared__ float red[8];
    __shared__ float stats[2];
    const int w = t >> 6, l = t & 63;
    if (l == 0) { red[w] = v1; red[4 + w] = v2; }
    __syncthreads();
    if (t == 0) {
        float su = red[0] + red[1] + red[2] + red[3];
        float sq = red[4] + red[5] + red[6] + red[7];
        float mu = su * (1.0f / 256.0f);
        float var = sq * (1.0f / 256.0f) - mu * mu;
        stats[0] = mu;
        stats[1] = rsqrtf(var + 1e-5f);
    }
    __syncthreads();
    float normed = (s - stats[0]) * stats[1] * ln_g[t] + ln_b[t];

    __shared__ float pr[40];
    #pragma unroll
    for (int c = 0; c < 10; c++) {
        float pv = normed * Wt[t * 10 + c];
        #pragma unroll
        for (int off = 32; off; off >>= 1) pv += __shfl_down(pv, off);
        if (l == 0) pr[w * 10 + c] = pv;
    }
    __syncthreads();
    if (t < 10)
        out[b * 10 + t] = pr[t] + pr[10 + t] + pr[20 + t] + pr[30 + t] + bt[t];
}

extern "C" void kernel_launch(void* const* d_in, const int* in_sizes, int n_in,
                              void* d_out, int out_size, void* d_ws, size_t ws_size,
                              hipStream_t stream)
{
    const float* x      = (const float*)d_in[0];
    const float* W1     = (const float*)d_in[1];
    const float* b1     = (const float*)d_in[2];
    const float* W2     = (const float*)d_in[3];
    const float* b2     = (const float*)d_in[4];
    const float* op_emb = (const float*)d_in[5];
    const float* ln_g   = (const float*)d_in[6];
    const float* ln_b   = (const float*)d_in[7];
    const float* Wt     = (const float*)d_in[8];
    const float* bt     = (const float*)d_in[9];
    const int* tempers  = (const int*)d_in[10];
    const int* ops      = (const int*)d_in[11];

    char* ws = (char*)d_ws;
    float* state          = (float*)(ws + OFF_STATE);
    float* c1             = (float*)(ws + OFF_C1);
    int* counts           = (int*)(ws + OFF_COUNTS);
    int* lists            = (int*)(ws + OFF_LISTS);
    int* jobs             = (int*)(ws + OFF_JOBS);
    int* njobs            = (int*)(ws + OFF_NJ);
    float* out            = (float*)d_out;

    prep_kernel<<<37, 256, 0, stream>>>(W1, b1, op_emb, tempers, ops,
                                        c1, counts, lists, jobs, njobs);
    for (int hop = 0; hop < HOPS; hop++)
        hop_kernel<<<100, 1024, 0, stream>>>(hop == 0 ? x : state, state,
                                             W1, W2, c1, b2,
                                             counts, lists, jobs, njobs, hop);
    final_kernel<<<128, 256, 0, stream>>>(x, state, tempers,
                                          ln_g, ln_b, Wt, bt, out);
}

// Round 11
// 141.754 us; speedup vs baseline: 1.1033x; 1.1033x over previous
//
#include <hip/hip_runtime.h>

typedef __attribute__((ext_vector_type(8))) short short8;
typedef __attribute__((ext_vector_type(4))) float floatx4;

// Problem constants
#define NEXP   36          // 12 tempers * 3 ops
#define NTOK   1024        // 128 batch * 8 patches
#define HOPS   4

// Workspace layout (bytes)
#define OFF_STATE   0u          // 1024*256*4      = 1,048,576
#define OFF_W1B     1048576u    // 36*65536*2      = 4,718,592 (bf16, swizzled)
#define OFF_W2B     5767168u    // 36*65536*2      = 4,718,592
#define OFF_C1      10485760u   // 36*256*4        = 36,864
#define OFF_COUNTS  10522624u   // 4*36*4          = 576
#define OFF_LISTS   10523264u   // 4*36*1024*4     = 589,824
#define OFF_JOBS    11113088u   // 4*128*4         = 2,048
#define OFF_NJ      11115136u   // 4*4             = 16   (end ~11.1 MB)

__device__ __forceinline__ unsigned short f2bf(float f) {
    unsigned u = __float_as_uint(f);
    u += 0x7FFFu + ((u >> 16) & 1u);   // round-to-nearest-even
    return (unsigned short)(u >> 16);
}

// ---------------------------------------------------------------------------
// PREP (rebuilt for latency hiding; 613 blocks):
//  block  0           : routing + job compaction (starts in scheduling round
//                       0, overlapped by the convert blocks — in r7 it sat at
//                       the grid tail and serialized after the converts)
//  blocks [1,577)     : weight convert, block=(mat,e,kb). Thread t owns
//                       column j=t: 32 scalar loads along k (4x the MLP of
//                       the r7 mapping) -> 64 B contiguous store into
//                       Wb[e][kb][j][k32]. Same 28 MB traffic, 4x deeper
//                       pipelining (r9 profile: 55 us at 384 GB/s = latency-
//                       bound, not BW-bound).
//  blocks [577,613)   : c1[e][j] = b1[e][j] + sum_k emb[e][k]*W1[e][256+k][j]
// ---------------------------------------------------------------------------
__global__ __launch_bounds__(256) void prep_kernel(
    const float* __restrict__ W1, const float* __restrict__ b1,
    const float* __restrict__ W2, const float* __restrict__ op_emb,
    const int* __restrict__ tempers, const int* __restrict__ ops,
    unsigned short* __restrict__ W1b, unsigned short* __restrict__ W2b,
    float* __restrict__ c1, int* __restrict__ counts, int* __restrict__ lists,
    int* __restrict__ jobs, int* __restrict__ njobs)
{
    const int bid = blockIdx.x;
    const int t = threadIdx.x;

    if (bid == 0) {
        // ---- routing (single block; cumulative-halt semantics) ----
        __shared__ int lc[HOPS * NEXP];
        if (t < HOPS * NEXP) lc[t] = 0;
        __syncthreads();
        for (int q = 0; q < 4; q++) {
            int n = q * 256 + t;
            bool act = true;
            for (int hop = 0; hop < HOPS; hop++) {
                int tt = tempers[hop * NTOK + n];
                int oo = ops[hop * NTOK + n];
                act = act && (tt != 12);       // 12 == halt; sticky
                if (act) {
                    int e = tt * 3 + oo;
                    int pos = atomicAdd(&lc[hop * NEXP + e], 1);
                    lists[(hop * NEXP + e) * NTOK + pos] = n;
                }
            }
        }
        __syncthreads();
        if (t < HOPS * NEXP) counts[t] = lc[t];
        // ---- job compaction: one thread per hop; job = (m0<<8)|e ----
        if (t < HOPS) {
            int hop = t, nj = 0;
            for (int e = 0; e < NEXP; e++) {
                int c = lc[hop * NEXP + e];
                for (int m0 = 0; m0 < c; m0 += 16)
                    jobs[hop * 128 + nj++] = (m0 << 8) | e;
            }
            njobs[hop] = nj;
        }
    } else if (bid < 577) {
        // ---- weight convert: block=(mat,e,kb), thread=column j ----
        const int id0 = bid - 1;               // 0..575
        const int mat = id0 / 288;             // 0: W1, 1: W2
        const int id  = id0 % 288;             // 36 experts * 8 kb
        const int e   = id / 8;
        const int kb  = id % 8;
        const float* src = mat ? (W2 + e * 65536) : (W1 + e * 98304);
        unsigned short* dst = (mat ? W2b : W1b) + e * 65536;
        const int j = t;
        float v[32];
        #pragma unroll
        for (int k32 = 0; k32 < 32; k32++)     // 32 loads in flight, 256B/instr
            v[k32] = src[(kb * 32 + k32) * 256 + j];
        unsigned short* dp = dst + (kb * 256 + j) * 32;
        #pragma unroll
        for (int q = 0; q < 4; q++) {          // 4 x 16B contiguous stores
            short8 pk;
            #pragma unroll
            for (int i = 0; i < 8; i++) pk[i] = (short)f2bf(v[q * 8 + i]);
            *(short8*)(dp + q * 8) = pk;
        }
    } else {
        // ---- c1 precompute (fp32) ----
        const int e = bid - 577;
        __shared__ float eb[128];
        if (t < 128) eb[t] = op_emb[e * 128 + t];
        __syncthreads();
        float acc = b1[e * 256 + t];
        const float* wp = W1 + e * 98304 + 256 * 256;  // emb rows of W1[e]
        #pragma unroll 4
        for (int k = 0; k < 128; k++)
            acc += eb[k] * wp[k * 256 + t];
        c1[e * 256 + t] = acc;
    }
}

// ---------------------------------------------------------------------------
// HOP: one job = (expert, 16-token tile), 1024 threads = 16 waves.
// Wave w owns output columns [w*16,w*16+16). B-frags preloaded from the
// bf16-swizzled buffer (16 B contiguous each) and pinned into registers
// (empty "+v" asm defeats load-sinking; r8 showed VGPR=60 without it).
//  GEMM1: h = relu(src_bf16 @ W1b + c1)   (c1 folds emb part + b1)
//  GEMM2: y = relu(h_bf16 @ W2b + b2)  -> state (f32)
// src = x for hop 0, state for hops 1..3 (sticky halt => rows valid).
// MFMA maps (m89): A[m=l&15][k=(l>>4)*8+i]; D col=l&15, row=(l>>4)*4+reg.
// ---------------------------------------------------------------------------
__global__ __launch_bounds__(1024, 4) void hop_kernel(
    const float* __restrict__ src, float* __restrict__ state,
    const unsigned short* __restrict__ W1b,
    const unsigned short* __restrict__ W2b,
    const float* __restrict__ c1, const float* __restrict__ b2,
    const int* __restrict__ counts, const int* __restrict__ lists,
    const int* __restrict__ jobs, const int* __restrict__ njobs, int hop)
{
    if (blockIdx.x >= njobs[hop]) return;  // uniform early-exit
    const int job = jobs[hop * 128 + blockIdx.x];
    const int e   = job & 0xFF;
    const int m0  = job >> 8;
    const int n_e = counts[hop * NEXP + e];
    const int mact = min(16, n_e - m0);

    const int t = threadIdx.x;
    const int l = t & 63, w = t >> 6;      // wave 0..15
    const int col = l & 15, g = l >> 4;
    const int j = w * 16 + col;            // this wave's output column

    // ---- preload B-frags for both GEMMs ----
    const unsigned short* Wp  = W1b + e * 65536;
    const unsigned short* Wp2 = W2b + e * 65536;
    short8 B1[8], B2[8];
    #pragma unroll
    for (int kb = 0; kb < 8; kb++) {
        B1[kb] = *(const short8*)(Wp  + (kb * 256 + j) * 32 + g * 8);
        B2[kb] = *(const short8*)(Wp2 + (kb * 256 + j) * 32 + g * 8);
    }
    // ---- force register materialization (defeat load sinking) ----
    #pragma unroll
    for (int kb = 0; kb < 8; kb++) {
        int4 p1 = __builtin_bit_cast(int4, B1[kb]);
        int4 p2 = __builtin_bit_cast(int4, B2[kb]);
        asm volatile("" : "+v"(p1.x), "+v"(p1.y), "+v"(p1.z), "+v"(p1.w),
                          "+v"(p2.x), "+v"(p2.y), "+v"(p2.z), "+v"(p2.w));
        B1[kb] = __builtin_bit_cast(short8, p1);
        B2[kb] = __builtin_bit_cast(short8, p2);
    }
    const float cv = c1[e * 256 + j];
    const float bv = b2[e * 256 + j];

    __shared__ int toks[16];
    __shared__ unsigned short Ab[4096];    // [kb][lane][8] bf16, 8 KB
    __shared__ unsigned short Hb[4096];    // 8 KB

    if (t < 16) toks[t] = (t < mact) ? lists[(hop * NEXP + e) * NTOK + m0 + t] : 0;
    __syncthreads();

    // ---- stage A tile: src rows (f32) -> bf16 in A-frag layout ----
    {
        int m = t >> 6;                    // token row 0..15 (one wave per row)
        int k = (t & 63) * 4;              // float4 column
        float4 v = make_float4(0.f, 0.f, 0.f, 0.f);
        if (m < mact) v = *(const float4*)(src + toks[m] * 256 + k);
        int kb = k >> 5, gg = (k >> 3) & 3, i = k & 7;
        unsigned short* d = Ab + kb * 512 + (gg * 16 + m) * 8 + i;
        d[0] = f2bf(v.x); d[1] = f2bf(v.y); d[2] = f2bf(v.z); d[3] = f2bf(v.w);
    }
    __syncthreads();

    // ---- GEMM1 (weights in registers) ----
    floatx4 acc = (floatx4){cv, cv, cv, cv};
    #pragma unroll
    for (int kb = 0; kb < 8; kb++) {
        short8 a = *(const short8*)(Ab + kb * 512 + l * 8);
        acc = __builtin_amdgcn_mfma_f32_16x16x32_bf16(a, B1[kb], acc, 0, 0, 0);
    }
    // ---- epilogue 1: relu -> Hb in A-frag layout (h-dim becomes K) ----
    {
        int kb2 = j >> 5, g2 = (j >> 3) & 3, i2 = j & 7;
        #pragma unroll
        for (int r = 0; r < 4; r++) {
            int m = g * 4 + r;             // D row (token)
            float vv = acc[r];
            vv = vv > 0.f ? vv : 0.f;
            Hb[kb2 * 512 + (g2 * 16 + m) * 8 + i2] = f2bf(vv);
        }
    }
    __syncthreads();

    // ---- GEMM2 ----
    floatx4 acc2 = (floatx4){bv, bv, bv, bv};
    #pragma unroll
    for (int kb = 0; kb < 8; kb++) {
        short8 a = *(const short8*)(Hb + kb * 512 + l * 8);
        acc2 = __builtin_amdgcn_mfma_f32_16x16x32_bf16(a, B2[kb], acc2, 0, 0, 0);
    }
    // ---- epilogue 2: relu -> state (f32), only real rows ----
    #pragma unroll
    for (int r = 0; r < 4; r++) {
        int m = g * 4 + r;
        if (m < mact) {
            float vv = acc2[r];
            state[toks[m] * 256 + j] = vv > 0.f ? vv : 0.f;
        }
    }
}

// ---------------------------------------------------------------------------
// FINAL: mean-pool 8 patches -> LayerNorm -> 10-class head. One block/batch.
// Tokens halted at hop 0 (tempers[0][n]==12) were never written -> read x.
// ---------------------------------------------------------------------------
__global__ __launch_bounds__(256) void final_kernel(
    const float* __restrict__ x, const float* __restrict__ state,
    const int* __restrict__ tempers,
    const float* __restrict__ ln_g, const float* __restrict__ ln_b,
    const float* __restrict__ Wt, const float* __restrict__ bt,
    float* __restrict__ out)
{
    const int b = blockIdx.x, t = threadIdx.x;
    float s = 0.f;
    #pragma unroll
    for (int p = 0; p < 8; p++) {
        int n = b * 8 + p;
        const float* rowsrc = (tempers[n] != 12) ? state : x;
        s += rowsrc[n * 256 + t];
    }
    s *= 0.125f;

    float v1 = s, v2 = s * s;
    #pragma unroll
    for (int off = 32; off; off >>= 1) {
        v1 += __shfl_down(v1, off);
        v2 += __shfl_down(v2, off);
    }
    __shared__ float red[8];
    __shared__ float stats[2];
    const int w = t >> 6, l = t & 63;
    if (l == 0) { red[w] = v1; red[4 + w] = v2; }
    __syncthreads();
    if (t == 0) {
        float su = red[0] + red[1] + red[2] + red[3];
        float sq = red[4] + red[5] + red[6] + red[7];
        float mu = su * (1.0f / 256.0f);
        float var = sq * (1.0f / 256.0f) - mu * mu;
        stats[0] = mu;
        stats[1] = rsqrtf(var + 1e-5f);
    }
    __syncthreads();
    float normed = (s - stats[0]) * stats[1] * ln_g[t] + ln_b[t];

    __shared__ float pr[40];
    #pragma unroll
    for (int c = 0; c < 10; c++) {
        float pv = normed * Wt[t * 10 + c];
        #pragma unroll
        for (int off = 32; off; off >>= 1) pv += __shfl_down(pv, off);
        if (l == 0) pr[w * 10 + c] = pv;
    }
    __syncthreads();
    if (t < 10)
        out[b * 10 + t] = pr[t] + pr[10 + t] + pr[20 + t] + pr[30 + t] + bt[t];
}

extern "C" void kernel_launch(void* const* d_in, const int* in_sizes, int n_in,
                              void* d_out, int out_size, void* d_ws, size_t ws_size,
                              hipStream_t stream)
{
    const float* x      = (const float*)d_in[0];
    const float* W1     = (const float*)d_in[1];
    const float* b1     = (const float*)d_in[2];
    const float* W2     = (const float*)d_in[3];
    const float* b2     = (const float*)d_in[4];
    const float* op_emb = (const float*)d_in[5];
    const float* ln_g   = (const float*)d_in[6];
    const float* ln_b   = (const float*)d_in[7];
    const float* Wt     = (const float*)d_in[8];
    const float* bt     = (const float*)d_in[9];
    const int* tempers  = (const int*)d_in[10];
    const int* ops      = (const int*)d_in[11];

    char* ws = (char*)d_ws;
    float* state          = (float*)(ws + OFF_STATE);
    unsigned short* W1b   = (unsigned short*)(ws + OFF_W1B);
    unsigned short* W2b   = (unsigned short*)(ws + OFF_W2B);
    float* c1             = (float*)(ws + OFF_C1);
    int* counts           = (int*)(ws + OFF_COUNTS);
    int* lists            = (int*)(ws + OFF_LISTS);
    int* jobs             = (int*)(ws + OFF_JOBS);
    int* njobs            = (int*)(ws + OFF_NJ);
    float* out            = (float*)d_out;

    prep_kernel<<<613, 256, 0, stream>>>(W1, b1, W2, op_emb, tempers, ops,
                                         W1b, W2b, c1, counts, lists,
                                         jobs, njobs);
    for (int hop = 0; hop < HOPS; hop++)
        hop_kernel<<<100, 1024, 0, stream>>>(hop == 0 ? x : state, state,
                                             W1b, W2b, c1, b2,
                                             counts, lists, jobs, njobs, hop);
    final_kernel<<<128, 256, 0, stream>>>(x, state, tempers,
                                          ln_g, ln_b, Wt, bt, out);
}